// Round 7
// baseline (841.818 us; speedup 1.0000x reference)
//
#include <hip/hip_runtime.h>
#include <math.h>

#define B_ 8
#define N_ 2048
#define D_ 3
#define H_ 256
#define ND_ (N_*D_)     // 6144
#define BN_ (B_*N_)     // 16384
#define NBARR_ (27*256) // 27 phases x 8 groups x 32-uint pad

struct SinkParams {
  float scl[14], kk[14], hh[14], c1[14], c2[14];
};

// ---------------- per-batch std (ddof=1) ----------------
__global__ __launch_bounds__(256) void std_kernel(const float* __restrict__ cloud,
                                                  float* __restrict__ stdv) {
  __shared__ float red[256];
  int b = blockIdx.x, tid = threadIdx.x;
  const float* p = cloud + (size_t)b * ND_;
  float s = 0.f;
  for (int i = tid; i < ND_; i += 256) s += p[i];
  red[tid] = s; __syncthreads();
  for (int off = 128; off > 0; off >>= 1) {
    if (tid < off) red[tid] += red[tid + off];
    __syncthreads();
  }
  float mean = red[0] / (float)ND_;
  __syncthreads();
  float ss = 0.f;
  for (int i = tid; i < ND_; i += 256) { float d = p[i] - mean; ss += d * d; }
  red[tid] = ss; __syncthreads();
  for (int off = 128; off > 0; off >>= 1) {
    if (tid < off) red[tid] += red[tid + off];
    __syncthreads();
  }
  if (tid == 0) stdv[b] = sqrtf(red[0] / (float)(ND_ - 1));
}

// ---------------- pack points, zero potentials + barrier counters ----------------
__global__ __launch_bounds__(256) void prep_kernel(const float* __restrict__ cloud,
    const float* __restrict__ noise, const float* __restrict__ stdv,
    float4* __restrict__ x0p, float4* __restrict__ np4,
    float* __restrict__ f, float* __restrict__ g, unsigned* __restrict__ barr) {
  int i = blockIdx.x * 256 + threadIdx.x;
  if (i < NBARR_) barr[i] = 0u;
  if (i >= BN_) return;
  int b = i >> 11;
  float sd = stdv[b];
  float cx = cloud[3*i] / sd, cy = cloud[3*i+1] / sd, cz = cloud[3*i+2] / sd;
  x0p[i] = make_float4(cx, cy, cz, cx*cx + cy*cy + cz*cz);
  float ax = noise[3*i], ay = noise[3*i+1], az = noise[3*i+2];
  np4[i] = make_float4(ax, ay, az, ax*ax + ay*ay + az*az);
  f[i] = 0.f; g[i] = 0.f;
}

// ---------------- persistent Sinkhorn with per-batch counter barriers ----------------
// R5's proven compute body (bit-identical f/g), but: XCD-affine decode (batch =
// blockIdx&7 -> a batch's 64 blocks share one XCD) and grid.sync() replaced by
// a per-(phase,batch) counter barrier (R5 lesson: grid.sync ~60us; batch-local
// barrier ~2us). Correctness is mapping-independent: pout stores and pin loads
// are agent-scope atomics (coherent at device scope); the XCD mapping is a
// performance heuristic only. Cooperative launch guarantees co-residency.
__global__ __launch_bounds__(256, 2) void sinkhorn_persist(
    const float4* __restrict__ x0p, const float4* __restrict__ np4,
    float* __restrict__ f, float* __restrict__ g,
    unsigned* __restrict__ barr, SinkParams P) {
  __shared__ float4 sP[N_];   // 32 KB
  int tid = threadIdx.x;
  int b = blockIdx.x & 7;                  // XCD-affine: batch == XCD id
  int rowBase = (blockIdx.x >> 3) << 5;    // 32 rows per block
  int base = b * N_;
  int wave = tid >> 6, lane = tid & 63;

  for (int it = 0; it < 14; ++it) {
    float scl = P.scl[it], kk = P.kk[it], hh = P.hh[it];
    float c1 = P.c1[it], c2 = P.c2[it];
#pragma unroll 1
    for (int ph = 0; ph < 2; ++ph) {
      const float4* outer = ph ? x0p : np4;
      const float4* inner = ph ? np4 : x0p;
      const float*  pin   = ph ? f : g;
      float*        pout  = ph ? g : f;

      for (int j = tid; j < N_; j += 256) {
        float4 p = inner[base + j];
        float pv = __hip_atomic_load(&pin[base + j], __ATOMIC_RELAXED,
                                     __HIP_MEMORY_SCOPE_AGENT);
        float q = kk * pv - hh * p.w;
        sP[j] = make_float4(scl * p.x, scl * p.y, scl * p.z, q);
      }
      __syncthreads();

#pragma unroll 1
      for (int rg = 0; rg < 2; ++rg) {
        int r0 = base + rowBase + (rg << 4) + (wave << 2);
        float4 A0 = outer[r0], A1 = outer[r0+1], A2 = outer[r0+2], A3 = outer[r0+3];
        float a0x = scl*A0.x, a0y = scl*A0.y, a0z = scl*A0.z, rc0 = -hh*A0.w;
        float a1x = scl*A1.x, a1y = scl*A1.y, a1z = scl*A1.z, rc1 = -hh*A1.w;
        float a2x = scl*A2.x, a2y = scl*A2.y, a2z = scl*A2.z, rc2 = -hh*A2.w;
        float a3x = scl*A3.x, a3y = scl*A3.y, a3z = scl*A3.z, rc3 = -hh*A3.w;
        float v0[32], v1[32], v2[32], v3[32];
        float m0 = -INFINITY, m1 = -INFINITY, m2 = -INFINITY, m3 = -INFINITY;
#pragma unroll
        for (int jj = 0; jj < 32; ++jj) {
          float4 p = sP[(jj << 6) + lane];
          float t0 = fmaf(p.x, a0x, p.w); t0 = fmaf(p.y, a0y, t0); t0 = fmaf(p.z, a0z, t0);
          v0[jj] = t0; m0 = fmaxf(m0, t0);
          float t1 = fmaf(p.x, a1x, p.w); t1 = fmaf(p.y, a1y, t1); t1 = fmaf(p.z, a1z, t1);
          v1[jj] = t1; m1 = fmaxf(m1, t1);
          float t2 = fmaf(p.x, a2x, p.w); t2 = fmaf(p.y, a2y, t2); t2 = fmaf(p.z, a2z, t2);
          v2[jj] = t2; m2 = fmaxf(m2, t2);
          float t3 = fmaf(p.x, a3x, p.w); t3 = fmaf(p.y, a3y, t3); t3 = fmaf(p.z, a3z, t3);
          v3[jj] = t3; m3 = fmaxf(m3, t3);
        }
#pragma unroll
        for (int off = 32; off >= 1; off >>= 1) {
          m0 = fmaxf(m0, __shfl_xor(m0, off, 64));
          m1 = fmaxf(m1, __shfl_xor(m1, off, 64));
          m2 = fmaxf(m2, __shfl_xor(m2, off, 64));
          m3 = fmaxf(m3, __shfl_xor(m3, off, 64));
        }
        float s0 = 0.f, s1 = 0.f, s2 = 0.f, s3 = 0.f;
#pragma unroll
        for (int jj = 0; jj < 32; ++jj) {
          s0 += __builtin_amdgcn_exp2f(v0[jj] - m0);
          s1 += __builtin_amdgcn_exp2f(v1[jj] - m1);
          s2 += __builtin_amdgcn_exp2f(v2[jj] - m2);
          s3 += __builtin_amdgcn_exp2f(v3[jj] - m3);
        }
#pragma unroll
        for (int off = 32; off >= 1; off >>= 1) {
          s0 += __shfl_xor(s0, off, 64);
          s1 += __shfl_xor(s1, off, 64);
          s2 += __shfl_xor(s2, off, 64);
          s3 += __shfl_xor(s3, off, 64);
        }
        if (lane == 0) {
          float o0 = fmaf(c1, rc0 + m0 + __builtin_amdgcn_logf(s0), c2);
          float o1 = fmaf(c1, rc1 + m1 + __builtin_amdgcn_logf(s1), c2);
          float o2 = fmaf(c1, rc2 + m2 + __builtin_amdgcn_logf(s2), c2);
          float o3 = fmaf(c1, rc3 + m3 + __builtin_amdgcn_logf(s3), c2);
          __hip_atomic_store(&pout[r0],   o0, __ATOMIC_RELAXED, __HIP_MEMORY_SCOPE_AGENT);
          __hip_atomic_store(&pout[r0+1], o1, __ATOMIC_RELAXED, __HIP_MEMORY_SCOPE_AGENT);
          __hip_atomic_store(&pout[r0+2], o2, __ATOMIC_RELAXED, __HIP_MEMORY_SCOPE_AGENT);
          __hip_atomic_store(&pout[r0+3], o3, __ATOMIC_RELAXED, __HIP_MEMORY_SCOPE_AGENT);
        }
      }

      int pidx = it * 2 + ph;
      if (pidx != 27) {
        __syncthreads();   // drains vmcnt: all this block's pout stores complete
        if (tid == 0) {
          unsigned* c = barr + pidx * 256 + b * 32;   // 128B pad per (phase,batch)
          __hip_atomic_fetch_add(c, 1u, __ATOMIC_ACQ_REL, __HIP_MEMORY_SCOPE_AGENT);
          while (__hip_atomic_load(c, __ATOMIC_ACQUIRE, __HIP_MEMORY_SCOPE_AGENT) < 64u)
            __builtin_amdgcn_s_sleep(1);
        }
        __syncthreads();   // release block; safe to restage sP / read pin
      }
    }
  }
}

// ---------------- fallback half-iteration (R6 verbatim, proven 389us path) ----------------
__global__ __launch_bounds__(512, 4) void lse_kernel(
    const float4* __restrict__ outer, const float4* __restrict__ inner,
    const float* __restrict__ pin, float* __restrict__ pout,
    float scl, float kk, float hh, float c1, float c2) {
  __shared__ float4 sP[N_];
  int tid = threadIdx.x;
  int b = blockIdx.x & 7;
  int rowBase = (blockIdx.x >> 3) << 4;
  int base = b * N_;
  for (int j = tid; j < N_; j += 512) {
    float4 p = inner[base + j];
    float q = kk * pin[base + j] - hh * p.w;
    sP[j] = make_float4(scl * p.x, scl * p.y, scl * p.z, q);
  }
  __syncthreads();
  int wave = tid >> 6, lane = tid & 63;
  int r0 = base + rowBase + (wave << 1);
  float4 A0 = outer[r0], A1 = outer[r0+1];
  float a0x = scl*A0.x, a0y = scl*A0.y, a0z = scl*A0.z, rc0 = -hh*A0.w;
  float a1x = scl*A1.x, a1y = scl*A1.y, a1z = scl*A1.z, rc1 = -hh*A1.w;
  float v0[32], v1[32];
  float m0 = -INFINITY, m1 = -INFINITY;
#pragma unroll
  for (int jj = 0; jj < 32; ++jj) {
    float4 p = sP[(jj << 6) + lane];
    float t0 = fmaf(p.x, a0x, p.w); t0 = fmaf(p.y, a0y, t0); t0 = fmaf(p.z, a0z, t0);
    v0[jj] = t0; m0 = fmaxf(m0, t0);
    float t1 = fmaf(p.x, a1x, p.w); t1 = fmaf(p.y, a1y, t1); t1 = fmaf(p.z, a1z, t1);
    v1[jj] = t1; m1 = fmaxf(m1, t1);
  }
#pragma unroll
  for (int off = 32; off >= 1; off >>= 1) {
    m0 = fmaxf(m0, __shfl_xor(m0, off, 64));
    m1 = fmaxf(m1, __shfl_xor(m1, off, 64));
  }
  float s0 = 0.f, s1 = 0.f;
#pragma unroll
  for (int jj = 0; jj < 32; ++jj) {
    s0 += __builtin_amdgcn_exp2f(v0[jj] - m0);
    s1 += __builtin_amdgcn_exp2f(v1[jj] - m1);
  }
#pragma unroll
  for (int off = 32; off >= 1; off >>= 1) {
    s0 += __shfl_xor(s0, off, 64);
    s1 += __shfl_xor(s1, off, 64);
  }
  if (lane == 0) {
    pout[r0]   = fmaf(c1, rc0 + m0 + __builtin_amdgcn_logf(s0), c2);
    pout[r0+1] = fmaf(c1, rc1 + m1 + __builtin_amdgcn_logf(s1), c2);
  }
}

// ---------------- fused argmin + gather + interp + MLP ----------------
// R6 body, widened to 512 thr / 32 rows / grid 512: halves tile-staging volume.
// Per-row math, tie-break, and output addresses identical -> bit-identical.
__global__ __launch_bounds__(512, 2) void assign_mlp_kernel(
    const float4* __restrict__ np4, const float4* __restrict__ x0p,
    const float* __restrict__ g, const float* __restrict__ t,
    const float* __restrict__ W1, const float* __restrict__ Wt,
    const float* __restrict__ b1, const float* __restrict__ W2,
    const float* __restrict__ b2, float* __restrict__ out) {
  __shared__ float4 sPts[N_];
  __shared__ float  sg[N_];
  __shared__ float  sW1[3*H_], sWt[H_], sb1[H_], sW2[H_*3], sb2[3];
  int tid = threadIdx.x;
  int b = blockIdx.x & 7;                  // XCD-affine
  int rowBase = (blockIdx.x >> 3) << 5;    // 32 rows per block
  int base = b * N_;
  for (int j = tid; j < N_; j += 512) { sPts[j] = x0p[base+j]; sg[j] = g[base+j]; }
  for (int i = tid; i < 3*H_; i += 512) { sW1[i] = W1[i]; sW2[i] = W2[i]; }
  if (tid < H_) { sWt[tid] = Wt[tid]; sb1[tid] = b1[tid]; }
  if (tid < 3) sb2[tid] = b2[tid];
  __syncthreads();
  int wave = tid >> 6, lane = tid & 63;
  int r0 = base + rowBase + (wave << 2);   // 8 waves x 4 rows
  float4 A0 = np4[r0], A1 = np4[r0+1], A2 = np4[r0+2], A3 = np4[r0+3];
  float b0 = INFINITY, b1v = INFINITY, b2v = INFINITY, b3v = INFINITY;
  int i0 = 0, i1 = 0, i2 = 0, i3 = 0;
#pragma unroll
  for (int jj = 0; jj < 32; ++jj) {
    int j = (jj << 6) + lane;
    float4 p = sPts[j];
    float gj = sg[j];
    float d0 = A0.x*p.x + A0.y*p.y + A0.z*p.z;
    float v0 = fmaxf(A0.w + p.w - 2.0f*d0, 0.0f) - gj;
    if (v0 < b0) { b0 = v0; i0 = j; }
    float d1 = A1.x*p.x + A1.y*p.y + A1.z*p.z;
    float v1 = fmaxf(A1.w + p.w - 2.0f*d1, 0.0f) - gj;
    if (v1 < b1v) { b1v = v1; i1 = j; }
    float d2 = A2.x*p.x + A2.y*p.y + A2.z*p.z;
    float v2 = fmaxf(A2.w + p.w - 2.0f*d2, 0.0f) - gj;
    if (v2 < b2v) { b2v = v2; i2 = j; }
    float d3 = A3.x*p.x + A3.y*p.y + A3.z*p.z;
    float v3 = fmaxf(A3.w + p.w - 2.0f*d3, 0.0f) - gj;
    if (v3 < b3v) { b3v = v3; i3 = j; }
  }
#pragma unroll
  for (int off = 32; off >= 1; off >>= 1) {
    float ov; int oi;
    ov = __shfl_xor(b0, off, 64);  oi = __shfl_xor(i0, off, 64);
    if (ov < b0 || (ov == b0 && oi < i0)) { b0 = ov; i0 = oi; }
    ov = __shfl_xor(b1v, off, 64); oi = __shfl_xor(i1, off, 64);
    if (ov < b1v || (ov == b1v && oi < i1)) { b1v = ov; i1 = oi; }
    ov = __shfl_xor(b2v, off, 64); oi = __shfl_xor(i2, off, 64);
    if (ov < b2v || (ov == b2v && oi < i2)) { b2v = ov; i2 = oi; }
    ov = __shfl_xor(b3v, off, 64); oi = __shfl_xor(i3, off, 64);
    if (ov < b3v || (ov == b3v && oi < i3)) { b3v = ov; i3 = oi; }
  }
  float tb = t[b];
  int idx[4] = {i0, i1, i2, i3};
  float4 Ar[4] = {A0, A1, A2, A3};
#pragma unroll
  for (int rr = 0; rr < 4; ++rr) {
    float4 A = Ar[rr];
    float4 xa = sPts[idx[rr]];
    float xtx = (1.0f - tb)*xa.x + tb*A.x;
    float xty = (1.0f - tb)*xa.y + tb*A.y;
    float xtz = (1.0f - tb)*xa.z + tb*A.z;
    float acc0 = 0.f, acc1 = 0.f, acc2 = 0.f;
#pragma unroll
    for (int hh = 0; hh < 4; ++hh) {
      int h = (hh << 6) + lane;
      float hv = xtx*sW1[h] + xty*sW1[H_+h] + xtz*sW1[2*H_+h] + tb*sWt[h] + sb1[h];
      hv = fmaxf(hv, 0.0f);
      acc0 += hv * sW2[3*h];
      acc1 += hv * sW2[3*h+1];
      acc2 += hv * sW2[3*h+2];
    }
#pragma unroll
    for (int off = 32; off >= 1; off >>= 1) {
      acc0 += __shfl_xor(acc0, off, 64);
      acc1 += __shfl_xor(acc1, off, 64);
      acc2 += __shfl_xor(acc2, off, 64);
    }
    if (lane == 0) {
      int gi = r0 + rr;
      out[3*gi]   = acc0 + sb2[0];
      out[3*gi+1] = acc1 + sb2[1];
      out[3*gi+2] = acc2 + sb2[2];
      out[3*BN_ + 3*gi]   = A.x - xa.x;
      out[3*BN_ + 3*gi+1] = A.y - xa.y;
      out[3*BN_ + 3*gi+2] = A.z - xa.z;
    }
  }
}

extern "C" void kernel_launch(void* const* d_in, const int* in_sizes, int n_in,
                              void* d_out, int out_size, void* d_ws, size_t ws_size,
                              hipStream_t stream) {
  (void)in_sizes; (void)n_in; (void)out_size; (void)ws_size;
  const float* cloud = (const float*)d_in[0];
  const float* noise = (const float*)d_in[1];
  const float* t     = (const float*)d_in[2];
  const float* W1    = (const float*)d_in[3];
  const float* Wt    = (const float*)d_in[4];
  const float* b1    = (const float*)d_in[5];
  const float* W2    = (const float*)d_in[6];
  const float* b2w   = (const float*)d_in[7];
  float* out = (float*)d_out;

  float* ws   = (float*)d_ws;
  float* stdv = ws;                         // 8 floats (pad to 16)
  float4* x0p = (float4*)(ws + 16);         // BN_ float4
  float4* np4 = (float4*)(ws + 16 + 4*BN_); // BN_ float4
  float* f    = ws + 16 + 8*BN_;            // BN_
  float* g    = f + BN_;                    // BN_
  unsigned* barr = (unsigned*)(g + BN_);    // NBARR_ uints

  std_kernel<<<B_, 256, 0, stream>>>(cloud, stdv);
  prep_kernel<<<BN_/256, 256, 0, stream>>>(cloud, noise, stdv, x0p, np4, f, g, barr);

  const double LOG2E = 1.4426950408889634074;
  const double LN2   = 0.6931471805599453094;
  const double logw  = -log(2048.0);          // loga == logb == -log(N)
  const double l0 = log10(32.0), l1 = log10(1e-6);
  SinkParams P;
  for (int kit = 0; kit < 14; ++kit) {
    // np.geomspace(32, 1e-6, 14) == 10**linspace(log10(32), -6, 14), cast fp32
    double epsd = pow(10.0, l0 + (l1 - l0) * ((double)kit / 13.0));
    float eps = (float)epsd;
    P.kk[kit]  = (float)(LOG2E / (double)eps);
    P.hh[kit]  = 0.5f * P.kk[kit];
    P.scl[kit] = sqrtf(P.kk[kit]);
    P.c1[kit]  = (float)(-(double)eps * LN2);
    P.c2[kit]  = (float)(-(double)eps * logw);
  }

  // persistent Sinkhorn (cooperative launch for residency guarantee; custom
  // batch-local barriers instead of grid.sync). Fallback: R6 dispatch chain.
  {
    void* args[] = { (void*)&x0p, (void*)&np4, (void*)&f, (void*)&g,
                     (void*)&barr, (void*)&P };
    hipError_t err = hipLaunchCooperativeKernel((const void*)sinkhorn_persist,
                                                dim3(512), dim3(256), args, 0, stream);
    if (err != hipSuccess) {
      (void)hipGetLastError();   // clear
      for (int kit = 0; kit < 14; ++kit) {
        lse_kernel<<<B_*(N_/16), 512, 0, stream>>>(np4, x0p, g, f,
            P.scl[kit], P.kk[kit], P.hh[kit], P.c1[kit], P.c2[kit]);
        lse_kernel<<<B_*(N_/16), 512, 0, stream>>>(x0p, np4, f, g,
            P.scl[kit], P.kk[kit], P.hh[kit], P.c1[kit], P.c2[kit]);
      }
    }
  }

  assign_mlp_kernel<<<B_*(N_/32), 512, 0, stream>>>(np4, x0p, g, t, W1, Wt, b1, W2, b2w, out);
}

// Round 8
// 455.184 us; speedup vs baseline: 1.8494x; 1.8494x over previous
//
#include <hip/hip_runtime.h>
#include <math.h>

#define B_ 8
#define N_ 2048
#define D_ 3
#define H_ 256
#define ND_ (N_*D_)     // 6144
#define BN_ (B_*N_)     // 16384

// ---------------- fused per-batch std (ddof=1) + pack + zero potentials ----------------
// One block per batch. The std reduction is the std_kernel body VERBATIM
// (same 256-thread strided sums, same tree) -> bit-identical sd. Packing uses
// prep_kernel's exact per-point formulas -> bit-identical x0p/np4.
__global__ __launch_bounds__(256) void stdprep_kernel(const float* __restrict__ cloud,
    const float* __restrict__ noise,
    float4* __restrict__ x0p, float4* __restrict__ np4,
    float* __restrict__ f, float* __restrict__ g) {
  __shared__ float red[256];
  int b = blockIdx.x, tid = threadIdx.x;
  const float* p = cloud + (size_t)b * ND_;
  float s = 0.f;
  for (int i = tid; i < ND_; i += 256) s += p[i];
  red[tid] = s; __syncthreads();
  for (int off = 128; off > 0; off >>= 1) {
    if (tid < off) red[tid] += red[tid + off];
    __syncthreads();
  }
  float mean = red[0] / (float)ND_;
  __syncthreads();
  float ss = 0.f;
  for (int i = tid; i < ND_; i += 256) { float d = p[i] - mean; ss += d * d; }
  red[tid] = ss; __syncthreads();
  for (int off = 128; off > 0; off >>= 1) {
    if (tid < off) red[tid] += red[tid + off];
    __syncthreads();
  }
  float sd = sqrtf(red[0] / (float)(ND_ - 1));
  int base = b * N_;
  for (int i = tid; i < N_; i += 256) {
    int gi = base + i;
    float cx = cloud[3*gi] / sd, cy = cloud[3*gi+1] / sd, cz = cloud[3*gi+2] / sd;
    x0p[gi] = make_float4(cx, cy, cz, cx*cx + cy*cy + cz*cz);
    float ax = noise[3*gi], ay = noise[3*gi+1], az = noise[3*gi+2];
    np4[gi] = make_float4(ax, ay, az, ax*ax + ay*ay + az*az);
    f[gi] = 0.f; g[gi] = 0.f;
  }
}

// ---------------- one Sinkhorn half-iteration (log2 domain) ----------------
// R6 VERBATIM (best measured, 389us total): 2 rows/wave, 512-thr blocks,
// grid 1024, XCD-affine batch map (batch = blockIdx&7 -> a batch's 128 blocks
// share one XCD, f/g/x0p/np4 stay hot in that XCD's L2 across dispatches).
// R5/R7 lesson: persistence (grid.sync OR custom barriers) costs far more than
// the kernel boundary; the 28-dispatch chain is the cheap sync.
__global__ __launch_bounds__(512, 4) void lse_kernel(
    const float4* __restrict__ outer, const float4* __restrict__ inner,
    const float* __restrict__ pin, float* __restrict__ pout,
    float scl, float kk, float hh, float c1, float c2) {
  __shared__ float4 sP[N_];   // 32 KB: scaled coords + q
  int tid = threadIdx.x;
  int b = blockIdx.x & 7;                  // XCD-affine: batch == XCD id
  int rowBase = (blockIdx.x >> 3) << 4;    // 16 rows per block
  int base = b * N_;
  for (int j = tid; j < N_; j += 512) {
    float4 p = inner[base + j];
    float q = kk * pin[base + j] - hh * p.w;
    sP[j] = make_float4(scl * p.x, scl * p.y, scl * p.z, q);
  }
  __syncthreads();
  int wave = tid >> 6, lane = tid & 63;
  int r0 = base + rowBase + (wave << 1);   // 2 rows per wave
  float4 A0 = outer[r0], A1 = outer[r0+1];
  float a0x = scl*A0.x, a0y = scl*A0.y, a0z = scl*A0.z, rc0 = -hh*A0.w;
  float a1x = scl*A1.x, a1y = scl*A1.y, a1z = scl*A1.z, rc1 = -hh*A1.w;
  float v0[32], v1[32];
  float m0 = -INFINITY, m1 = -INFINITY;
#pragma unroll
  for (int jj = 0; jj < 32; ++jj) {
    float4 p = sP[(jj << 6) + lane];
    float t0 = fmaf(p.x, a0x, p.w); t0 = fmaf(p.y, a0y, t0); t0 = fmaf(p.z, a0z, t0);
    v0[jj] = t0; m0 = fmaxf(m0, t0);
    float t1 = fmaf(p.x, a1x, p.w); t1 = fmaf(p.y, a1y, t1); t1 = fmaf(p.z, a1z, t1);
    v1[jj] = t1; m1 = fmaxf(m1, t1);
  }
#pragma unroll
  for (int off = 32; off >= 1; off >>= 1) {
    m0 = fmaxf(m0, __shfl_xor(m0, off, 64));
    m1 = fmaxf(m1, __shfl_xor(m1, off, 64));
  }
  float s0 = 0.f, s1 = 0.f;
#pragma unroll
  for (int jj = 0; jj < 32; ++jj) {
    s0 += __builtin_amdgcn_exp2f(v0[jj] - m0);
    s1 += __builtin_amdgcn_exp2f(v1[jj] - m1);
  }
#pragma unroll
  for (int off = 32; off >= 1; off >>= 1) {
    s0 += __shfl_xor(s0, off, 64);
    s1 += __shfl_xor(s1, off, 64);
  }
  if (lane == 0) {
    pout[r0]   = fmaf(c1, rc0 + m0 + __builtin_amdgcn_logf(s0), c2);
    pout[r0+1] = fmaf(c1, rc1 + m1 + __builtin_amdgcn_logf(s1), c2);
  }
}

// ---------------- fused argmin(sqdist - g) + gather + interp + MLP ----------------
// R6 body with the LDS diet: only sPts+sg staged (40KB -> exactly 4 blocks/CU,
// single resident round; was 49.6KB -> 3/CU + ragged 2nd round, Occ 10%, 41us).
// Weights read directly from global (5KB, L2-hot broadcast), hoisted hh-OUTER
// so each weight loads once per wave instead of 4x. Expression trees,
// per-row accumulation order (h = hh*64+lane ascending), tie-break and write
// order textually identical -> bit-identical output.
__global__ __launch_bounds__(256, 4) void assign_mlp_kernel(
    const float4* __restrict__ np4, const float4* __restrict__ x0p,
    const float* __restrict__ g, const float* __restrict__ t,
    const float* __restrict__ W1, const float* __restrict__ Wt,
    const float* __restrict__ b1, const float* __restrict__ W2,
    const float* __restrict__ b2, float* __restrict__ out) {
  __shared__ float4 sPts[N_];   // 32 KB
  __shared__ float  sg[N_];     //  8 KB
  int tid = threadIdx.x;
  int b = blockIdx.x & 7;                  // XCD-affine
  int rowBase = (blockIdx.x >> 3) << 4;    // 16 rows per block
  int base = b * N_;
  for (int j = tid; j < N_; j += 256) { sPts[j] = x0p[base+j]; sg[j] = g[base+j]; }
  __syncthreads();
  int wave = tid >> 6, lane = tid & 63;
  int r0 = base + rowBase + (wave << 2);
  float4 A0 = np4[r0], A1 = np4[r0+1], A2 = np4[r0+2], A3 = np4[r0+3];
  float b0 = INFINITY, b1v = INFINITY, b2v = INFINITY, b3v = INFINITY;
  int i0 = 0, i1 = 0, i2 = 0, i3 = 0;
#pragma unroll
  for (int jj = 0; jj < 32; ++jj) {
    int j = (jj << 6) + lane;
    float4 p = sPts[j];
    float gj = sg[j];
    float d0 = A0.x*p.x + A0.y*p.y + A0.z*p.z;
    float v0 = fmaxf(A0.w + p.w - 2.0f*d0, 0.0f) - gj;
    if (v0 < b0) { b0 = v0; i0 = j; }         // strict < keeps lowest j per lane
    float d1 = A1.x*p.x + A1.y*p.y + A1.z*p.z;
    float v1 = fmaxf(A1.w + p.w - 2.0f*d1, 0.0f) - gj;
    if (v1 < b1v) { b1v = v1; i1 = j; }
    float d2 = A2.x*p.x + A2.y*p.y + A2.z*p.z;
    float v2 = fmaxf(A2.w + p.w - 2.0f*d2, 0.0f) - gj;
    if (v2 < b2v) { b2v = v2; i2 = j; }
    float d3 = A3.x*p.x + A3.y*p.y + A3.z*p.z;
    float v3 = fmaxf(A3.w + p.w - 2.0f*d3, 0.0f) - gj;
    if (v3 < b3v) { b3v = v3; i3 = j; }
  }
#pragma unroll
  for (int off = 32; off >= 1; off >>= 1) {
    float ov; int oi;
    ov = __shfl_xor(b0, off, 64);  oi = __shfl_xor(i0, off, 64);
    if (ov < b0 || (ov == b0 && oi < i0)) { b0 = ov; i0 = oi; }
    ov = __shfl_xor(b1v, off, 64); oi = __shfl_xor(i1, off, 64);
    if (ov < b1v || (ov == b1v && oi < i1)) { b1v = ov; i1 = oi; }
    ov = __shfl_xor(b2v, off, 64); oi = __shfl_xor(i2, off, 64);
    if (ov < b2v || (ov == b2v && oi < i2)) { b2v = ov; i2 = oi; }
    ov = __shfl_xor(b3v, off, 64); oi = __shfl_xor(i3, off, 64);
    if (ov < b3v || (ov == b3v && oi < i3)) { b3v = ov; i3 = oi; }
  }
  float tb = t[b];
  float4 xa0 = sPts[i0], xa1 = sPts[i1], xa2 = sPts[i2], xa3 = sPts[i3];
  float xtx0 = (1.0f - tb)*xa0.x + tb*A0.x, xty0 = (1.0f - tb)*xa0.y + tb*A0.y, xtz0 = (1.0f - tb)*xa0.z + tb*A0.z;
  float xtx1 = (1.0f - tb)*xa1.x + tb*A1.x, xty1 = (1.0f - tb)*xa1.y + tb*A1.y, xtz1 = (1.0f - tb)*xa1.z + tb*A1.z;
  float xtx2 = (1.0f - tb)*xa2.x + tb*A2.x, xty2 = (1.0f - tb)*xa2.y + tb*A2.y, xtz2 = (1.0f - tb)*xa2.z + tb*A2.z;
  float xtx3 = (1.0f - tb)*xa3.x + tb*A3.x, xty3 = (1.0f - tb)*xa3.y + tb*A3.y, xtz3 = (1.0f - tb)*xa3.z + tb*A3.z;
  float acc00 = 0.f, acc01 = 0.f, acc02 = 0.f;
  float acc10 = 0.f, acc11 = 0.f, acc12 = 0.f;
  float acc20 = 0.f, acc21 = 0.f, acc22 = 0.f;
  float acc30 = 0.f, acc31 = 0.f, acc32 = 0.f;
#pragma unroll
  for (int hh = 0; hh < 4; ++hh) {
    int h = (hh << 6) + lane;
    float w1a = W1[h], w1b = W1[H_+h], w1c = W1[2*H_+h];
    float wt_ = Wt[h], b1_ = b1[h];
    float w20 = W2[3*h], w21 = W2[3*h+1], w22 = W2[3*h+2];
    float hv0 = xtx0*w1a + xty0*w1b + xtz0*w1c + tb*wt_ + b1_;
    hv0 = fmaxf(hv0, 0.0f);
    acc00 += hv0 * w20; acc01 += hv0 * w21; acc02 += hv0 * w22;
    float hv1 = xtx1*w1a + xty1*w1b + xtz1*w1c + tb*wt_ + b1_;
    hv1 = fmaxf(hv1, 0.0f);
    acc10 += hv1 * w20; acc11 += hv1 * w21; acc12 += hv1 * w22;
    float hv2 = xtx2*w1a + xty2*w1b + xtz2*w1c + tb*wt_ + b1_;
    hv2 = fmaxf(hv2, 0.0f);
    acc20 += hv2 * w20; acc21 += hv2 * w21; acc22 += hv2 * w22;
    float hv3 = xtx3*w1a + xty3*w1b + xtz3*w1c + tb*wt_ + b1_;
    hv3 = fmaxf(hv3, 0.0f);
    acc30 += hv3 * w20; acc31 += hv3 * w21; acc32 += hv3 * w22;
  }
#pragma unroll
  for (int off = 32; off >= 1; off >>= 1) {
    acc00 += __shfl_xor(acc00, off, 64);
    acc01 += __shfl_xor(acc01, off, 64);
    acc02 += __shfl_xor(acc02, off, 64);
  }
#pragma unroll
  for (int off = 32; off >= 1; off >>= 1) {
    acc10 += __shfl_xor(acc10, off, 64);
    acc11 += __shfl_xor(acc11, off, 64);
    acc12 += __shfl_xor(acc12, off, 64);
  }
#pragma unroll
  for (int off = 32; off >= 1; off >>= 1) {
    acc20 += __shfl_xor(acc20, off, 64);
    acc21 += __shfl_xor(acc21, off, 64);
    acc22 += __shfl_xor(acc22, off, 64);
  }
#pragma unroll
  for (int off = 32; off >= 1; off >>= 1) {
    acc30 += __shfl_xor(acc30, off, 64);
    acc31 += __shfl_xor(acc31, off, 64);
    acc32 += __shfl_xor(acc32, off, 64);
  }
  if (lane == 0) {
    float bb0 = b2[0], bb1 = b2[1], bb2 = b2[2];
    int gi = r0;
    out[3*gi]   = acc00 + bb0; out[3*gi+1] = acc01 + bb1; out[3*gi+2] = acc02 + bb2;
    out[3*BN_ + 3*gi]   = A0.x - xa0.x;
    out[3*BN_ + 3*gi+1] = A0.y - xa0.y;
    out[3*BN_ + 3*gi+2] = A0.z - xa0.z;
    gi = r0 + 1;
    out[3*gi]   = acc10 + bb0; out[3*gi+1] = acc11 + bb1; out[3*gi+2] = acc12 + bb2;
    out[3*BN_ + 3*gi]   = A1.x - xa1.x;
    out[3*BN_ + 3*gi+1] = A1.y - xa1.y;
    out[3*BN_ + 3*gi+2] = A1.z - xa1.z;
    gi = r0 + 2;
    out[3*gi]   = acc20 + bb0; out[3*gi+1] = acc21 + bb1; out[3*gi+2] = acc22 + bb2;
    out[3*BN_ + 3*gi]   = A2.x - xa2.x;
    out[3*BN_ + 3*gi+1] = A2.y - xa2.y;
    out[3*BN_ + 3*gi+2] = A2.z - xa2.z;
    gi = r0 + 3;
    out[3*gi]   = acc30 + bb0; out[3*gi+1] = acc31 + bb1; out[3*gi+2] = acc32 + bb2;
    out[3*BN_ + 3*gi]   = A3.x - xa3.x;
    out[3*BN_ + 3*gi+1] = A3.y - xa3.y;
    out[3*BN_ + 3*gi+2] = A3.z - xa3.z;
  }
}

extern "C" void kernel_launch(void* const* d_in, const int* in_sizes, int n_in,
                              void* d_out, int out_size, void* d_ws, size_t ws_size,
                              hipStream_t stream) {
  (void)in_sizes; (void)n_in; (void)out_size; (void)ws_size;
  const float* cloud = (const float*)d_in[0];
  const float* noise = (const float*)d_in[1];
  const float* t     = (const float*)d_in[2];
  const float* W1    = (const float*)d_in[3];
  const float* Wt    = (const float*)d_in[4];
  const float* b1    = (const float*)d_in[5];
  const float* W2    = (const float*)d_in[6];
  const float* b2w   = (const float*)d_in[7];
  float* out = (float*)d_out;

  float* ws   = (float*)d_ws;
  float4* x0p = (float4*)(ws + 16);         // BN_ float4
  float4* np4 = (float4*)(ws + 16 + 4*BN_); // BN_ float4
  float* f    = ws + 16 + 8*BN_;            // BN_
  float* g    = f + BN_;                    // BN_

  stdprep_kernel<<<B_, 256, 0, stream>>>(cloud, noise, x0p, np4, f, g);

  const double LOG2E = 1.4426950408889634074;
  const double LN2   = 0.6931471805599453094;
  const double logw  = -log(2048.0);          // loga == logb == -log(N)
  const double l0 = log10(32.0), l1 = log10(1e-6);
  for (int kit = 0; kit < 14; ++kit) {
    // np.geomspace(32, 1e-6, 14) == 10**linspace(log10(32), -6, 14), cast fp32
    double epsd = pow(10.0, l0 + (l1 - l0) * ((double)kit / 13.0));
    float eps = (float)epsd;
    float kk  = (float)(LOG2E / (double)eps);
    float hh  = 0.5f * kk;
    float scl = sqrtf(kk);
    float c1  = (float)(-(double)eps * LN2);
    float c2  = (float)(-(double)eps * logw);
    // f = -eps*lse_j(logb + (g - C)/eps): rows = noise, inner = x0/g
    lse_kernel<<<B_*(N_/16), 512, 0, stream>>>(np4, x0p, g, f, scl, kk, hh, c1, c2);
    // g = -eps*lse_i(loga + (f - C)/eps): rows = x0, inner = noise/f
    lse_kernel<<<B_*(N_/16), 512, 0, stream>>>(x0p, np4, f, g, scl, kk, hh, c1, c2);
  }

  assign_mlp_kernel<<<B_*(N_/16), 256, 0, stream>>>(np4, x0p, g, t, W1, Wt, b1, W2, b2w, out);
}

// Round 9
// 388.520 us; speedup vs baseline: 2.1667x; 1.1716x over previous
//
#include <hip/hip_runtime.h>
#include <math.h>

#define B_ 8
#define N_ 2048
#define D_ 3
#define H_ 256
#define ND_ (N_*D_)     // 6144
#define BN_ (B_*N_)     // 16384

// ---------------- fused per-batch std (ddof=1) + pack + zero potentials ----------------
// One block per batch. std reduction and packing formulas verbatim from the
// verified split kernels -> bit-identical sd / x0p / np4.
__global__ __launch_bounds__(256) void stdprep_kernel(const float* __restrict__ cloud,
    const float* __restrict__ noise,
    float4* __restrict__ x0p, float4* __restrict__ np4,
    float* __restrict__ f, float* __restrict__ g) {
  __shared__ float red[256];
  int b = blockIdx.x, tid = threadIdx.x;
  const float* p = cloud + (size_t)b * ND_;
  float s = 0.f;
  for (int i = tid; i < ND_; i += 256) s += p[i];
  red[tid] = s; __syncthreads();
  for (int off = 128; off > 0; off >>= 1) {
    if (tid < off) red[tid] += red[tid + off];
    __syncthreads();
  }
  float mean = red[0] / (float)ND_;
  __syncthreads();
  float ss = 0.f;
  for (int i = tid; i < ND_; i += 256) { float d = p[i] - mean; ss += d * d; }
  red[tid] = ss; __syncthreads();
  for (int off = 128; off > 0; off >>= 1) {
    if (tid < off) red[tid] += red[tid + off];
    __syncthreads();
  }
  float sd = sqrtf(red[0] / (float)(ND_ - 1));
  int base = b * N_;
  for (int i = tid; i < N_; i += 256) {
    int gi = base + i;
    float cx = cloud[3*gi] / sd, cy = cloud[3*gi+1] / sd, cz = cloud[3*gi+2] / sd;
    x0p[gi] = make_float4(cx, cy, cz, cx*cx + cy*cy + cz*cz);
    float ax = noise[3*gi], ay = noise[3*gi+1], az = noise[3*gi+2];
    np4[gi] = make_float4(ax, ay, az, ax*ax + ay*ay + az*az);
    f[gi] = 0.f; g[gi] = 0.f;
  }
}

// ---------------- one Sinkhorn half-iteration (log2 domain) ----------------
// R6 VERBATIM (best measured, 389.3us total): 2 rows/wave, 512-thr blocks,
// grid 1024 (exactly 4 blocks/CU, one resident round), XCD-affine batch map
// (batch = blockIdx&7: a batch's 128 blocks share one XCD -> f/g/x0p/np4 stay
// hot in that XCD's L2 across all 28 dispatches).
// Lessons pinned: R2 - never recompute pass-2 chains (2x DS+VALU = 2x time);
// R5/R7 - persistence (grid.sync or custom barriers) costs >> kernel boundary;
// the 28-dispatch chain IS the cheap sync. lse is LDS-throughput-bound.
__global__ __launch_bounds__(512, 4) void lse_kernel(
    const float4* __restrict__ outer, const float4* __restrict__ inner,
    const float* __restrict__ pin, float* __restrict__ pout,
    float scl, float kk, float hh, float c1, float c2) {
  __shared__ float4 sP[N_];   // 32 KB: scaled coords + q
  int tid = threadIdx.x;
  int b = blockIdx.x & 7;                  // XCD-affine: batch == XCD id
  int rowBase = (blockIdx.x >> 3) << 4;    // 16 rows per block
  int base = b * N_;
  for (int j = tid; j < N_; j += 512) {
    float4 p = inner[base + j];
    float q = kk * pin[base + j] - hh * p.w;
    sP[j] = make_float4(scl * p.x, scl * p.y, scl * p.z, q);
  }
  __syncthreads();
  int wave = tid >> 6, lane = tid & 63;
  int r0 = base + rowBase + (wave << 1);   // 2 rows per wave
  float4 A0 = outer[r0], A1 = outer[r0+1];
  float a0x = scl*A0.x, a0y = scl*A0.y, a0z = scl*A0.z, rc0 = -hh*A0.w;
  float a1x = scl*A1.x, a1y = scl*A1.y, a1z = scl*A1.z, rc1 = -hh*A1.w;
  float v0[32], v1[32];
  float m0 = -INFINITY, m1 = -INFINITY;
#pragma unroll
  for (int jj = 0; jj < 32; ++jj) {
    float4 p = sP[(jj << 6) + lane];
    float t0 = fmaf(p.x, a0x, p.w); t0 = fmaf(p.y, a0y, t0); t0 = fmaf(p.z, a0z, t0);
    v0[jj] = t0; m0 = fmaxf(m0, t0);
    float t1 = fmaf(p.x, a1x, p.w); t1 = fmaf(p.y, a1y, t1); t1 = fmaf(p.z, a1z, t1);
    v1[jj] = t1; m1 = fmaxf(m1, t1);
  }
#pragma unroll
  for (int off = 32; off >= 1; off >>= 1) {
    m0 = fmaxf(m0, __shfl_xor(m0, off, 64));
    m1 = fmaxf(m1, __shfl_xor(m1, off, 64));
  }
  float s0 = 0.f, s1 = 0.f;
#pragma unroll
  for (int jj = 0; jj < 32; ++jj) {
    s0 += __builtin_amdgcn_exp2f(v0[jj] - m0);
    s1 += __builtin_amdgcn_exp2f(v1[jj] - m1);
  }
#pragma unroll
  for (int off = 32; off >= 1; off >>= 1) {
    s0 += __shfl_xor(s0, off, 64);
    s1 += __shfl_xor(s1, off, 64);
  }
  if (lane == 0) {
    pout[r0]   = fmaf(c1, rc0 + m0 + __builtin_amdgcn_logf(s0), c2);
    pout[r0+1] = fmaf(c1, rc1 + m1 + __builtin_amdgcn_logf(s1), c2);
  }
}

// ---------------- fused argmin(sqdist - g) + gather + interp + MLP ----------------
// R6 VERBATIM. Do NOT restructure: both deviations tried (R3 split + workspace
// write; R8 LDS-diet + global weights at 4 blocks/CU) regressed to 100-160us
// with ~220MB FETCH in-window (HBM victim of harness poison traffic). This
// 49.6KB-LDS / 3-blocks-per-CU shape measured 44.5/43.0/41.2us across R1/R4/R6
// and stays L2-resident.
__global__ __launch_bounds__(256) void assign_mlp_kernel(
    const float4* __restrict__ np4, const float4* __restrict__ x0p,
    const float* __restrict__ g, const float* __restrict__ t,
    const float* __restrict__ W1, const float* __restrict__ Wt,
    const float* __restrict__ b1, const float* __restrict__ W2,
    const float* __restrict__ b2, float* __restrict__ out) {
  __shared__ float4 sPts[N_];
  __shared__ float  sg[N_];
  __shared__ float  sW1[3*H_], sWt[H_], sb1[H_], sW2[H_*3], sb2[3];
  int tid = threadIdx.x;
  int b = blockIdx.x & 7;                  // XCD-affine
  int rowBase = (blockIdx.x >> 3) << 4;    // 16 rows per block
  int base = b * N_;
  for (int j = tid; j < N_; j += 256) { sPts[j] = x0p[base+j]; sg[j] = g[base+j]; }
  for (int i = tid; i < 3*H_; i += 256) { sW1[i] = W1[i]; sW2[i] = W2[i]; }
  if (tid < H_) { sWt[tid] = Wt[tid]; sb1[tid] = b1[tid]; }
  if (tid < 3) sb2[tid] = b2[tid];
  __syncthreads();
  int wave = tid >> 6, lane = tid & 63;
  int r0 = base + rowBase + (wave << 2);
  float4 A0 = np4[r0], A1 = np4[r0+1], A2 = np4[r0+2], A3 = np4[r0+3];
  float b0 = INFINITY, b1v = INFINITY, b2v = INFINITY, b3v = INFINITY;
  int i0 = 0, i1 = 0, i2 = 0, i3 = 0;
#pragma unroll
  for (int jj = 0; jj < 32; ++jj) {
    int j = (jj << 6) + lane;
    float4 p = sPts[j];
    float gj = sg[j];
    float d0 = A0.x*p.x + A0.y*p.y + A0.z*p.z;
    float v0 = fmaxf(A0.w + p.w - 2.0f*d0, 0.0f) - gj;
    if (v0 < b0) { b0 = v0; i0 = j; }         // strict < keeps lowest j per lane
    float d1 = A1.x*p.x + A1.y*p.y + A1.z*p.z;
    float v1 = fmaxf(A1.w + p.w - 2.0f*d1, 0.0f) - gj;
    if (v1 < b1v) { b1v = v1; i1 = j; }
    float d2 = A2.x*p.x + A2.y*p.y + A2.z*p.z;
    float v2 = fmaxf(A2.w + p.w - 2.0f*d2, 0.0f) - gj;
    if (v2 < b2v) { b2v = v2; i2 = j; }
    float d3 = A3.x*p.x + A3.y*p.y + A3.z*p.z;
    float v3 = fmaxf(A3.w + p.w - 2.0f*d3, 0.0f) - gj;
    if (v3 < b3v) { b3v = v3; i3 = j; }
  }
#pragma unroll
  for (int off = 32; off >= 1; off >>= 1) {
    float ov; int oi;
    ov = __shfl_xor(b0, off, 64);  oi = __shfl_xor(i0, off, 64);
    if (ov < b0 || (ov == b0 && oi < i0)) { b0 = ov; i0 = oi; }
    ov = __shfl_xor(b1v, off, 64); oi = __shfl_xor(i1, off, 64);
    if (ov < b1v || (ov == b1v && oi < i1)) { b1v = ov; i1 = oi; }
    ov = __shfl_xor(b2v, off, 64); oi = __shfl_xor(i2, off, 64);
    if (ov < b2v || (ov == b2v && oi < i2)) { b2v = ov; i2 = oi; }
    ov = __shfl_xor(b3v, off, 64); oi = __shfl_xor(i3, off, 64);
    if (ov < b3v || (ov == b3v && oi < i3)) { b3v = ov; i3 = oi; }
  }
  float tb = t[b];
  int idx[4] = {i0, i1, i2, i3};
  float4 Ar[4] = {A0, A1, A2, A3};
#pragma unroll
  for (int rr = 0; rr < 4; ++rr) {
    float4 A = Ar[rr];
    float4 xa = sPts[idx[rr]];
    float xtx = (1.0f - tb)*xa.x + tb*A.x;
    float xty = (1.0f - tb)*xa.y + tb*A.y;
    float xtz = (1.0f - tb)*xa.z + tb*A.z;
    float acc0 = 0.f, acc1 = 0.f, acc2 = 0.f;
#pragma unroll
    for (int hh = 0; hh < 4; ++hh) {
      int h = (hh << 6) + lane;
      float hv = xtx*sW1[h] + xty*sW1[H_+h] + xtz*sW1[2*H_+h] + tb*sWt[h] + sb1[h];
      hv = fmaxf(hv, 0.0f);
      acc0 += hv * sW2[3*h];
      acc1 += hv * sW2[3*h+1];
      acc2 += hv * sW2[3*h+2];
    }
#pragma unroll
    for (int off = 32; off >= 1; off >>= 1) {
      acc0 += __shfl_xor(acc0, off, 64);
      acc1 += __shfl_xor(acc1, off, 64);
      acc2 += __shfl_xor(acc2, off, 64);
    }
    if (lane == 0) {
      int gi = r0 + rr;
      out[3*gi]   = acc0 + sb2[0];
      out[3*gi+1] = acc1 + sb2[1];
      out[3*gi+2] = acc2 + sb2[2];
      out[3*BN_ + 3*gi]   = A.x - xa.x;
      out[3*BN_ + 3*gi+1] = A.y - xa.y;
      out[3*BN_ + 3*gi+2] = A.z - xa.z;
    }
  }
}

extern "C" void kernel_launch(void* const* d_in, const int* in_sizes, int n_in,
                              void* d_out, int out_size, void* d_ws, size_t ws_size,
                              hipStream_t stream) {
  (void)in_sizes; (void)n_in; (void)out_size; (void)ws_size;
  const float* cloud = (const float*)d_in[0];
  const float* noise = (const float*)d_in[1];
  const float* t     = (const float*)d_in[2];
  const float* W1    = (const float*)d_in[3];
  const float* Wt    = (const float*)d_in[4];
  const float* b1    = (const float*)d_in[5];
  const float* W2    = (const float*)d_in[6];
  const float* b2w   = (const float*)d_in[7];
  float* out = (float*)d_out;

  float* ws   = (float*)d_ws;
  float4* x0p = (float4*)(ws + 16);         // BN_ float4
  float4* np4 = (float4*)(ws + 16 + 4*BN_); // BN_ float4
  float* f    = ws + 16 + 8*BN_;            // BN_
  float* g    = f + BN_;                    // BN_

  stdprep_kernel<<<B_, 256, 0, stream>>>(cloud, noise, x0p, np4, f, g);

  const double LOG2E = 1.4426950408889634074;
  const double LN2   = 0.6931471805599453094;
  const double logw  = -log(2048.0);          // loga == logb == -log(N)
  const double l0 = log10(32.0), l1 = log10(1e-6);
  for (int kit = 0; kit < 14; ++kit) {
    // np.geomspace(32, 1e-6, 14) == 10**linspace(log10(32), -6, 14), cast fp32
    double epsd = pow(10.0, l0 + (l1 - l0) * ((double)kit / 13.0));
    float eps = (float)epsd;
    float kk  = (float)(LOG2E / (double)eps);
    float hh  = 0.5f * kk;
    float scl = sqrtf(kk);
    float c1  = (float)(-(double)eps * LN2);
    float c2  = (float)(-(double)eps * logw);
    // f = -eps*lse_j(logb + (g - C)/eps): rows = noise, inner = x0/g
    lse_kernel<<<B_*(N_/16), 512, 0, stream>>>(np4, x0p, g, f, scl, kk, hh, c1, c2);
    // g = -eps*lse_i(loga + (f - C)/eps): rows = x0, inner = noise/f
    lse_kernel<<<B_*(N_/16), 512, 0, stream>>>(x0p, np4, f, g, scl, kk, hh, c1, c2);
  }

  assign_mlp_kernel<<<B_*(N_/16), 256, 0, stream>>>(np4, x0p, g, t, W1, Wt, b1, W2, b2w, out);
}